// Round 13
// baseline (2247.641 us; speedup 1.0000x reference)
//
#include <hip/hip_runtime.h>
#include <hip/hip_bf16.h>

#define NB   4
#define NPTS 16384
#define NC   64
#define NM   1024
#define NK   32
#define NCP  67
#define RAD2 0.25f

// workspace offsets in 4-byte units (total ~585k floats = 2.34 MB)
#define OFF_W0T     0u        // 67*128 = 8576
#define OFF_W1T     8576u     // 128*256 = 32768
#define OFF_NEWXYZ  41344u    // 12288
#define OFF_IDXBALL 53632u    // 4*1024*32 = 131072 (int)
#define OFF_CNT     184704u   // 65536 (int)
#define OFF_EMB     250240u   // 384
#define OFF_PW      250624u   // 4096
#define OFF_PE      254720u   // 68608 -> ends 323328
#define OFF_SX      323328u   // 65536 (sorted x, 4 batches)
#define OFF_SY      388864u   // 65536
#define OFF_SZ      454400u   // 65536
#define OFF_SKLO    519936u   // 65536 (u32) -> ends 585472

// output offsets (FLOAT32 elements; d_out is float*)
#define OUT_NEWXYZ 0u
#define OUT_POOLED 12288u
#define OUT_IDX    1060864u

// ---------------- transpose weights ----------------
__global__ __launch_bounds__(256) void k_prepw(const float* __restrict__ w0,
                                               const float* __restrict__ w1,
                                               float* __restrict__ w0t,
                                               float* __restrict__ w1t) {
  int t = blockIdx.x * 256 + threadIdx.x;
  if (t < 128 * NCP) { int o = t / NCP, c = t % NCP; w0t[c * 128 + o] = w0[t]; }
  if (t < 256 * 128) { int o2 = t / 128, o = t % 128; w1t[o * 256 + o2] = w1[t]; }
}

// ---------------- Morton counting-sort (per batch) ----------------
// 9-bit Morton cell (3 bits/dim over [-1,1)); counting sort via LDS histogram
// + prefix + atomic scatter. Within-cell order is nondeterministic, but FPS
// output is invariant to bucketing (per-point md/key math is exact and the
// argmax key is order-independent), so kernel_launch stays deterministic.
__device__ __forceinline__ unsigned mpart3(unsigned v) {
  return (v & 1u) | ((v & 2u) << 2) | ((v & 4u) << 4);
}
__device__ __forceinline__ unsigned cellof(float x, float y, float z) {
  unsigned qx = (unsigned)fminf(fmaxf((x + 1.0f) * 4.0f, 0.0f), 7.0f);
  unsigned qy = (unsigned)fminf(fmaxf((y + 1.0f) * 4.0f, 0.0f), 7.0f);
  unsigned qz = (unsigned)fminf(fmaxf((z + 1.0f) * 4.0f, 0.0f), 7.0f);
  return mpart3(qx) | (mpart3(qy) << 1) | (mpart3(qz) << 2);
}

__global__ __launch_bounds__(1024) void k_sort(const float* __restrict__ xyz,
                                               float* __restrict__ sx,
                                               float* __restrict__ sy,
                                               float* __restrict__ sz,
                                               unsigned* __restrict__ sklo) {
  const int b = blockIdx.x, t = threadIdx.x;
  const int lane = t & 63, wid = t >> 6;
  const float* xb = xyz + (size_t)b * NPTS * 3;
  __shared__ unsigned s_hist[512], s_off[512], s_wsum[8];
  if (t < 512) s_hist[t] = 0u;
  __syncthreads();
#pragma unroll
  for (int i = 0; i < 16; ++i) {
    int p = t + 1024 * i;
    float x = xb[p * 3 + 0], y = xb[p * 3 + 1], z = xb[p * 3 + 2];
    atomicAdd(&s_hist[cellof(x, y, z)], 1u);
  }
  __syncthreads();
  unsigned v = (t < 512) ? s_hist[t] : 0u;
#pragma unroll
  for (int off = 1; off < 64; off <<= 1) {
    unsigned u = __shfl_up(v, off);
    if (lane >= off) v += u;
  }
  if (t < 512 && lane == 63) s_wsum[wid] = v;
  __syncthreads();
  if (t < 512) {
    unsigned add = 0;
    for (int w = 0; w < wid; ++w) add += s_wsum[w];
    s_off[t] = add + v - s_hist[t];   // exclusive prefix
  }
  __syncthreads();
#pragma unroll
  for (int i = 0; i < 16; ++i) {
    int p = t + 1024 * i;
    float x = xb[p * 3 + 0], y = xb[p * 3 + 1], z = xb[p * 3 + 2];
    unsigned pos = atomicAdd(&s_off[cellof(x, y, z)], 1u);
    sx[b * NPTS + pos] = x;
    sy[b * NPTS + pos] = y;
    sz[b * NPTS + pos] = z;
    sklo[b * NPTS + pos] = 16383u - (unsigned)p;
  }
}

// ---------------- furthest point sampling (bucketized, exact) ----------------
// 256 buckets x 64 sorted points; md in LDS; per-bucket cached max-key + bbox.
// Per step: A) prune buckets with rigorous f32 lower bound (2^-16 two-sided
// margin covers d2's <=5-ulp rounding -> skipping provably equals computing
// min(md,d2)=md); B) unpruned buckets (1 wave each) update md + cached key;
// C) fold 256 cached keys. Key = (f32bits(md)<<32 | 16383-orig_idx): u64 max
// == (max value, min original index) == jnp.argmax semantics, and is
// order/partition-independent -> bucketing cannot change the output.
__device__ __forceinline__ unsigned long long umax64(unsigned long long a,
                                                     unsigned long long b) {
  return a > b ? a : b;
}

__global__ __launch_bounds__(1024) void k_fps(const float* __restrict__ xyz,
                                              const float* __restrict__ sx,
                                              const float* __restrict__ sy,
                                              const float* __restrict__ sz,
                                              const unsigned* __restrict__ sklo,
                                              float* __restrict__ newxyz,
                                              float* __restrict__ out) {
  const int b = blockIdx.x, t = threadIdx.x;
  const int lane = t & 63, wid = t >> 6;
  const float* xb = xyz + (size_t)b * NPTS * 3;
  const float* bx = sx + b * NPTS;
  const float* by_ = sy + b * NPTS;
  const float* bz_ = sz + b * NPTS;
  const unsigned* bk = sklo + b * NPTS;
  __shared__ float s_md[NPTS];                 // 64 KiB
  __shared__ unsigned short s_klo[NPTS];       // 32 KiB
  __shared__ float s_bbox[256][6];             // 6 KiB
  __shared__ unsigned long long s_bkey[256];   // 2 KiB
  __shared__ int s_list[2][256];
  __shared__ int s_cnt[2];
#pragma unroll
  for (int i = 0; i < 16; ++i) {
    int p = t + 1024 * i;
    s_md[p] = 1e10f;
    s_klo[p] = (unsigned short)bk[p];
  }
  if (t < 256) s_bkey[t] = ((unsigned long long)__float_as_uint(1e10f)) << 32;
  if (t < 2) s_cnt[t] = 0;
  // per-bucket bbox (wave w handles buckets w, w+16, ...)
  for (int bb = wid; bb < 256; bb += 16) {
    int p = bb * 64 + lane;
    float x = bx[p], y = by_[p], z = bz_[p];
    float xl = x, xh = x, yl = y, yh = y, zl = z, zh = z;
#pragma unroll
    for (int off = 1; off < 64; off <<= 1) {
      xl = fminf(xl, __shfl_xor(xl, off)); xh = fmaxf(xh, __shfl_xor(xh, off));
      yl = fminf(yl, __shfl_xor(yl, off)); yh = fmaxf(yh, __shfl_xor(yh, off));
      zl = fminf(zl, __shfl_xor(zl, off)); zh = fmaxf(zh, __shfl_xor(zh, off));
    }
    if (lane == 0) {
      s_bbox[bb][0] = xl; s_bbox[bb][1] = xh;
      s_bbox[bb][2] = yl; s_bbox[bb][3] = yh;
      s_bbox[bb][4] = zl; s_bbox[bb][5] = zh;
    }
  }
  float lx = xb[0], ly = xb[1], lz = xb[2];
  if (t == 0) {
    newxyz[(size_t)b * NM * 3 + 0] = lx;
    newxyz[(size_t)b * NM * 3 + 1] = ly;
    newxyz[(size_t)b * NM * 3 + 2] = lz;
    out[OUT_NEWXYZ + (size_t)b * NM * 3 + 0] = lx;
    out[OUT_NEWXYZ + (size_t)b * NM * 3 + 1] = ly;
    out[OUT_NEWXYZ + (size_t)b * NM * 3 + 2] = lz;
    out[OUT_IDX + b * NM] = 0.0f;
  }
  __syncthreads();
  for (int s = 1; s < NM; ++s) {
    const int pp = s & 1;
    // Phase A: prune test per bucket (threads 0..255); build unordered list
    if (t == 256) s_cnt[pp ^ 1] = 0;  // reset other step's counter
    if (t < 256) {
      float mm = __uint_as_float((unsigned)(s_bkey[t] >> 32));
      float gx = fmaxf(fmaxf(__fsub_rn(s_bbox[t][0], lx), __fsub_rn(lx, s_bbox[t][1])), 0.0f);
      float gy = fmaxf(fmaxf(__fsub_rn(s_bbox[t][2], ly), __fsub_rn(ly, s_bbox[t][3])), 0.0f);
      float gz = fmaxf(fmaxf(__fsub_rn(s_bbox[t][4], lz), __fsub_rn(lz, s_bbox[t][5])), 0.0f);
      float lb = __fadd_rn(__fadd_rn(__fmul_rn(gx, gx), __fmul_rn(gy, gy)),
                           __fmul_rn(gz, gz));
      // keep unless lb strictly dominates with 2^-16 two-sided margin
      if (!(lb * 0.999984741f > mm * 1.000015259f)) {
        int pos = atomicAdd(&s_cnt[pp], 1);
        s_list[pp][pos] = t;
      }
    }
    __syncthreads();
    const int nb = s_cnt[pp];
    // Phase B: one wave per unpruned bucket
    for (int w = wid; w < nb; w += 16) {
      int bb = s_list[pp][w];
      int p = bb * 64 + lane;
      float dx = __fsub_rn(bx[p], lx);
      float dy = __fsub_rn(by_[p], ly);
      float dz = __fsub_rn(bz_[p], lz);
      float d2 = __fadd_rn(__fadd_rn(__fmul_rn(dx, dx), __fmul_rn(dy, dy)),
                           __fmul_rn(dz, dz));
      float m0 = fminf(s_md[p], d2);
      s_md[p] = m0;
      unsigned long long key =
          (((unsigned long long)__float_as_uint(m0)) << 32) |
          (unsigned long long)s_klo[p];
#pragma unroll
      for (int off = 1; off < 64; off <<= 1) {
        unsigned long long o = __shfl_xor(key, off);
        key = o > key ? o : key;
      }
      if (lane == 0) s_bkey[bb] = key;
    }
    __syncthreads();
    // Phase C: global argmax over 256 cached keys (all waves, redundant)
    unsigned long long k =
        umax64(umax64(s_bkey[lane], s_bkey[lane + 64]),
               umax64(s_bkey[lane + 128], s_bkey[lane + 192]));
#pragma unroll
    for (int off = 1; off < 64; off <<= 1) {
      unsigned long long o = __shfl_xor(k, off);
      k = o > k ? o : k;
    }
    const int bi = 16383 - (int)(unsigned)(k & 0xffffffffull);
    lx = xb[bi * 3 + 0];
    ly = xb[bi * 3 + 1];
    lz = xb[bi * 3 + 2];
    if (t == 0) {
      newxyz[((size_t)b * NM + s) * 3 + 0] = lx;
      newxyz[((size_t)b * NM + s) * 3 + 1] = ly;
      newxyz[((size_t)b * NM + s) * 3 + 2] = lz;
      out[OUT_NEWXYZ + ((size_t)b * NM + s) * 3 + 0] = lx;
      out[OUT_NEWXYZ + ((size_t)b * NM + s) * 3 + 1] = ly;
      out[OUT_NEWXYZ + ((size_t)b * NM + s) * 3 + 2] = lz;
      out[OUT_IDX + b * NM + s] = (float)bi;
    }
  }
}

// ---------------- ball query: first NK indices with d2<=r2, pad with first ----
// one wave per (b,m); also histogram counts + xyz partial sums for emb.
__global__ __launch_bounds__(256) void k_ball(const float* __restrict__ xyz,
                                              const float* __restrict__ newxyz,
                                              int* __restrict__ idxball,
                                              int* __restrict__ cnt,
                                              float* __restrict__ emb) {
  __shared__ int s_idx[4][NK];
  const int lane = threadIdx.x & 63, wid = threadIdx.x >> 6;
  const int gid = blockIdx.x * 4 + wid; // (b,m)
  const int b = gid >> 10;
  const float* xb = xyz + (size_t)b * NPTS * 3;
  const float cx = newxyz[gid * 3 + 0];
  const float cy = newxyz[gid * 3 + 1];
  const float cz = newxyz[gid * 3 + 2];
  int total = 0;
  for (int base = 0; base < NPTS && total < NK; base += 64) {
    int n = base + lane;
    float dx = __fsub_rn(xb[n * 3 + 0], cx);
    float dy = __fsub_rn(xb[n * 3 + 1], cy);
    float dz = __fsub_rn(xb[n * 3 + 2], cz);
    float d2 = __fadd_rn(__fadd_rn(__fmul_rn(dx, dx), __fmul_rn(dy, dy)),
                         __fmul_rn(dz, dz));
    bool hit = d2 <= RAD2;
    unsigned long long mask = __ballot(hit);
    int pos = total + (int)__popcll(mask & ((1ull << lane) - 1ull));
    if (hit && pos < NK) s_idx[wid][pos] = n;
    total += (int)__popcll(mask);
  }
  int tt = total < NK ? total : NK;
  if (lane >= tt && lane < NK) s_idx[wid][lane] = s_idx[wid][0];
  int v = 0;
  if (lane < NK) {
    v = s_idx[wid][lane];
    idxball[(size_t)gid * NK + lane] = v;
    atomicAdd(&cnt[b * NPTS + v], 1);
  }
  float sx = 0.f, sy = 0.f, sz = 0.f;
  if (lane < NK) { sx = xb[v * 3 + 0]; sy = xb[v * 3 + 1]; sz = xb[v * 3 + 2]; }
#pragma unroll
  for (int off = 1; off < 64; off <<= 1) {
    sx += __shfl_xor(sx, off);
    sy += __shfl_xor(sy, off);
    sz += __shfl_xor(sz, off);
  }
  if (lane == 0) {
    atomicAdd(&emb[b * 96 + 0], sx - 32.0f * cx);
    atomicAdd(&emb[b * 96 + 1], sy - 32.0f * cy);
    atomicAdd(&emb[b * 96 + 2], sz - 32.0f * cz);
  }
}

// ---------------- emb feature part: emb[b,3+c] = sum_n cnt[b,n]*feat[b,c,n] ----
__global__ __launch_bounds__(256) void k_embfeat(const float* __restrict__ feat,
                                                 const int* __restrict__ cnt,
                                                 float* __restrict__ emb) {
  const int c = blockIdx.x, b = blockIdx.y;
  const float* f = feat + ((size_t)b * NC + c) * NPTS;
  const int* ct = cnt + b * NPTS;
  float acc = 0.f;
  for (int n = threadIdx.x; n < NPTS; n += 256)
    acc = fmaf((float)ct[n], f[n], acc);
  __shared__ float red[4];
#pragma unroll
  for (int off = 1; off < 64; off <<= 1) acc += __shfl_xor(acc, off);
  if ((threadIdx.x & 63) == 0) red[threadIdx.x >> 6] = acc;
  __syncthreads();
  if (threadIdx.x == 0)
    emb[b * 96 + 3 + c] = red[0] + red[1] + red[2] + red[3];
}

// ---------------- pe: proj + layernorm + exact gelu ----------------
__global__ __launch_bounds__(64) void k_pe(const float* __restrict__ prompt,
                                           const float* __restrict__ projw,
                                           const float* __restrict__ projb,
                                           const float* __restrict__ lng,
                                           const float* __restrict__ lnb,
                                           float* __restrict__ pe) {
  const int m = blockIdx.x, lane = threadIdx.x;
  const float p0 = prompt[m * 2 + 0], p1 = prompt[m * 2 + 1];
  const int c1 = lane, c2 = lane + 64;
  float v1 = p0 * projw[c1 * 2 + 0] + p1 * projw[c1 * 2 + 1] + projb[c1];
  float v2 = 0.f;
  if (c2 < NCP) v2 = p0 * projw[c2 * 2 + 0] + p1 * projw[c2 * 2 + 1] + projb[c2];
  float s = v1 + ((c2 < NCP) ? v2 : 0.f);
#pragma unroll
  for (int off = 1; off < 64; off <<= 1) s += __shfl_xor(s, off);
  float mu = s * (1.0f / 67.0f);
  float d1 = v1 - mu;
  float d2v = (c2 < NCP) ? (v2 - mu) : 0.f;
  float q = d1 * d1 + d2v * d2v;
#pragma unroll
  for (int off = 1; off < 64; off <<= 1) q += __shfl_xor(q, off);
  float inv = 1.0f / sqrtf(q * (1.0f / 67.0f) + 1e-5f);
  {
    float y = d1 * inv * lng[c1] + lnb[c1];
    pe[m * NCP + c1] = 0.5f * y * (1.0f + erff(y * 0.70710678118654752f));
  }
  if (c2 < NCP) {
    float y = (v2 - mu) * inv * lng[c2] + lnb[c2];
    pe[m * NCP + c2] = 0.5f * y * (1.0f + erff(y * 0.70710678118654752f));
  }
}

// ---------------- pw: softmax(emb/32768 @ pw_w.T + pw_b) ----------------
__global__ __launch_bounds__(1024) void k_pw(const float* __restrict__ emb,
                                             const float* __restrict__ pww,
                                             const float* __restrict__ pwb,
                                             float* __restrict__ pw) {
  const int b = blockIdx.x, m = threadIdx.x;
  __shared__ float se[NCP];
  __shared__ float red[16];
  __shared__ float bcast;
  if (m < NCP) se[m] = emb[b * 96 + m] * (1.0f / 32768.0f);
  __syncthreads();
  float acc = pwb[m];
  for (int c = 0; c < NCP; ++c) acc = fmaf(se[c], pww[m * NCP + c], acc);
  float mx = acc;
#pragma unroll
  for (int off = 1; off < 64; off <<= 1) mx = fmaxf(mx, __shfl_xor(mx, off));
  if ((m & 63) == 0) red[m >> 6] = mx;
  __syncthreads();
  if (m == 0) {
    float v = red[0];
    for (int w = 1; w < 16; ++w) v = fmaxf(v, red[w]);
    bcast = v;
  }
  __syncthreads();
  float e = expf(acc - bcast);
  float ssum = e;
#pragma unroll
  for (int off = 1; off < 64; off <<= 1) ssum += __shfl_xor(ssum, off);
  if ((m & 63) == 0) red[m >> 6] = ssum;
  __syncthreads();
  if (m == 0) {
    float v = 0.f;
    for (int w = 0; w < 16; ++w) v += red[w];
    bcast = v;
  }
  __syncthreads();
  pw[b * NM + m] = e / bcast;
}

// ---------------- fused gather + pe*pw + conv0 + conv1 + maxpool ----------------
__global__ __launch_bounds__(256) void k_main(const float* __restrict__ feat,
                                              const float* __restrict__ xyz,
                                              const float* __restrict__ newxyz,
                                              const int* __restrict__ idxball,
                                              const float* __restrict__ pe,
                                              const float* __restrict__ pwbuf,
                                              const float* __restrict__ w0t,
                                              const float* __restrict__ b0,
                                              const float* __restrict__ w1t,
                                              const float* __restrict__ b1,
                                              float* __restrict__ out) {
  __shared__ __align__(16) float g[NCP * 36];
  __shared__ __align__(16) float h0[128 * 36];
  __shared__ int s_idx[NK];
  __shared__ float spe[NCP];
  const int bid = blockIdx.x;
  const int b = bid >> 10, m = bid & 1023;
  const int t = threadIdx.x;
  const float pwv = pwbuf[bid];
  if (t < NK) {
    int n = idxball[(size_t)bid * NK + t];
    n = n < 0 ? 0 : (n > NPTS - 1 ? NPTS - 1 : n); // insurance clamp
    s_idx[t] = n;
  }
  if (t < NCP) spe[t] = pe[m * NCP + t] * pwv;
  __syncthreads();
  // stage feature rows of g (gather from native (B,C,N) layout; L3-resident)
  for (int e = t; e < NK * NC; e += 256) {
    int k = e >> 6, c = e & 63;
    int n = s_idx[k];
    g[(3 + c) * 36 + k] = feat[((size_t)b * NC + c) * NPTS + n] + spe[3 + c];
  }
  // stage xyz rows of g
  if (t < 96) {
    int k = t & 31, d = t >> 5;
    int n = s_idx[k];
    float cv = newxyz[bid * 3 + d];
    g[d * 36 + k] = (xyz[((size_t)b * NPTS + n) * 3 + d] - cv) + spe[d];
  }
  __syncthreads();
  // layer0: h0[o][k] = relu(sum_c W0[o,c]*g[c,k] + b0[o])
  {
    const int o = t & 127, kb = (t >> 7) * 16;
    float acc[16];
    float bb = b0[o];
#pragma unroll
    for (int j = 0; j < 16; ++j) acc[j] = bb;
    for (int c = 0; c < NCP; ++c) {
      float w = w0t[c * 128 + o];
      const float4* gp = reinterpret_cast<const float4*>(&g[c * 36 + kb]);
#pragma unroll
      for (int qq = 0; qq < 4; ++qq) {
        float4 gv = gp[qq];
        acc[qq * 4 + 0] = fmaf(w, gv.x, acc[qq * 4 + 0]);
        acc[qq * 4 + 1] = fmaf(w, gv.y, acc[qq * 4 + 1]);
        acc[qq * 4 + 2] = fmaf(w, gv.z, acc[qq * 4 + 2]);
        acc[qq * 4 + 3] = fmaf(w, gv.w, acc[qq * 4 + 3]);
      }
    }
    float4* hp = reinterpret_cast<float4*>(&h0[o * 36 + kb]);
#pragma unroll
    for (int qq = 0; qq < 4; ++qq) {
      float4 hv;
      hv.x = fmaxf(acc[qq * 4 + 0], 0.f);
      hv.y = fmaxf(acc[qq * 4 + 1], 0.f);
      hv.z = fmaxf(acc[qq * 4 + 2], 0.f);
      hv.w = fmaxf(acc[qq * 4 + 3], 0.f);
      hp[qq] = hv;
    }
  }
  __syncthreads();
  // layer1: pooled[o2] = max_k relu(sum_o W1[o2,o]*h0[o,k] + b1[o2])
  {
    const int o2 = t;
    float acc[32];
    float bb = b1[o2];
#pragma unroll
    for (int j = 0; j < 32; ++j) acc[j] = bb;
    for (int o = 0; o < 128; ++o) {
      float w = w1t[o * 256 + o2];
      const float4* hp = reinterpret_cast<const float4*>(&h0[o * 36]);
#pragma unroll
      for (int qq = 0; qq < 8; ++qq) {
        float4 hv = hp[qq];
        acc[qq * 4 + 0] = fmaf(w, hv.x, acc[qq * 4 + 0]);
        acc[qq * 4 + 1] = fmaf(w, hv.y, acc[qq * 4 + 1]);
        acc[qq * 4 + 2] = fmaf(w, hv.z, acc[qq * 4 + 2]);
        acc[qq * 4 + 3] = fmaf(w, hv.w, acc[qq * 4 + 3]);
      }
    }
    float mx = 0.f; // relu floor
#pragma unroll
    for (int k = 0; k < 32; ++k) mx = fmaxf(mx, acc[k]);
    out[OUT_POOLED + ((size_t)(b * 256 + o2)) * NM + m] = mx;
  }
}

extern "C" void kernel_launch(void* const* d_in, const int* in_sizes, int n_in,
                              void* d_out, int out_size, void* d_ws, size_t ws_size,
                              hipStream_t stream) {
  const float* xyz    = (const float*)d_in[0];
  const float* feat   = (const float*)d_in[1];
  const float* prompt = (const float*)d_in[2];
  const float* projw  = (const float*)d_in[3];
  const float* projb  = (const float*)d_in[4];
  const float* lng    = (const float*)d_in[5];
  const float* lnb    = (const float*)d_in[6];
  const float* pww    = (const float*)d_in[7];
  const float* pwb    = (const float*)d_in[8];
  const float* w0     = (const float*)d_in[9];
  const float* b0     = (const float*)d_in[10];
  const float* w1     = (const float*)d_in[11];
  const float* b1     = (const float*)d_in[12];
  float* ws = (float*)d_ws;
  float* out = (float*)d_out;

  float* w0t      = ws + OFF_W0T;
  float* w1t      = ws + OFF_W1T;
  float* nxyz     = ws + OFF_NEWXYZ;
  int*   idxball  = (int*)(ws + OFF_IDXBALL);
  int*   cnt      = (int*)(ws + OFF_CNT);
  float* emb      = ws + OFF_EMB;
  float* pwv      = ws + OFF_PW;
  float* pev      = ws + OFF_PE;
  float* sxw      = ws + OFF_SX;
  float* syw      = ws + OFF_SY;
  float* szw      = ws + OFF_SZ;
  unsigned* sklo  = (unsigned*)(ws + OFF_SKLO);

  hipMemsetAsync(cnt, 0, NB * NPTS * sizeof(int), stream);
  hipMemsetAsync(emb, 0, NB * 96 * sizeof(float), stream);

  k_prepw<<<128, 256, 0, stream>>>(w0, w1, w0t, w1t);
  k_sort<<<NB, 1024, 0, stream>>>(xyz, sxw, syw, szw, sklo);
  k_fps<<<NB, 1024, 0, stream>>>(xyz, sxw, syw, szw, sklo, nxyz, out);
  k_ball<<<NB * NM / 4, 256, 0, stream>>>(xyz, nxyz, idxball, cnt, emb);
  k_embfeat<<<dim3(NC, NB), 256, 0, stream>>>(feat, cnt, emb);
  k_pe<<<NM, 64, 0, stream>>>(prompt, projw, projb, lng, lnb, pev);
  k_pw<<<NB, 1024, 0, stream>>>(emb, pww, pwb, pwv);
  k_main<<<NB * NM, 256, 0, stream>>>(feat, xyz, nxyz, idxball, pev, pwv,
                                      w0t, b0, w1t, b1, out);
}